// Round 3
// baseline (238.952 us; speedup 1.0000x reference)
//
#include <hip/hip_runtime.h>

#define D 100
#define YSTRIDE 128   // bf16 row stride in elements (256 B = 64 uints)
#define BSHIFT 7      // 128 dst nodes per bucket
#define BSIZE 128
#define BMASK 127
#define NBKMAX 512    // supports N <= 65536
#define EPB 2048      // edges per block in bucket passes
#define DCAP 4096     // per-bucket staging capacity in phase D

typedef __attribute__((ext_vector_type(8))) short bf8v;
typedef __attribute__((ext_vector_type(4))) float f4v;

__device__ inline unsigned short f2bf(float f) {
    unsigned u = __float_as_uint(f);
    return (unsigned short)((u + 0x7fffu + ((u >> 16) & 1u)) >> 16);  // RNE
}
__device__ inline float bflo(unsigned v) { return __uint_as_float(v << 16); }
__device__ inline float bfhi(unsigned v) { return __uint_as_float(v & 0xffff0000u); }
// fp8 e4m3 (OCP on gfx950) helpers
__device__ inline unsigned short pk8(float a, float b) {
    return (unsigned short)(__builtin_amdgcn_cvt_pk_fp8_f32(a, b, 0, false) & 0xffff);
}

// accumulate 4 fp8 values (bytes of a uint) into a0..a3, weighted
__device__ inline void acc4(float& a0, float& a1, float& a2, float& a3, unsigned v, float w) {
    a0 = fmaf(__builtin_amdgcn_cvt_f32_fp8((int)v, 0), w, a0);
    a1 = fmaf(__builtin_amdgcn_cvt_f32_fp8((int)v, 1), w, a1);
    a2 = fmaf(__builtin_amdgcn_cvt_f32_fp8((int)v, 2), w, a2);
    a3 = fmaf(__builtin_amdgcn_cvt_f32_fp8((int)v, 3), w, a3);
}

// exclusive scan of a[0..512) in LDS, t[256] scratch; 256 threads
__device__ inline void scan512_excl(int* a, int* t, int tid) {
    int v0 = a[2 * tid], v1 = a[2 * tid + 1];
    t[tid] = v0 + v1;
    __syncthreads();
    for (int off = 1; off < 256; off <<= 1) {
        int u = (tid >= off) ? t[tid - off] : 0;
        __syncthreads();
        t[tid] += u;
        __syncthreads();
    }
    int base = (tid ? t[tid - 1] : 0);
    a[2 * tid]     = base;
    a[2 * tid + 1] = base + v0;
    __syncthreads();
}

// ---------------- fused preamble: pack x0->fp8 half-rows | bucketA | Wc=W2*W1 ----------------
// s8 half-rows: 16 uints = 64 B each; half array footprint N*64B = 3.2 MB (< 4 MB XCD L2).
// uint q of a full row holds dims 4q..4q+3; q<16 -> lo array, q>=16 -> hi array.
__global__ __launch_bounds__(256) void k_pre(const float* __restrict__ x0, const float* __restrict__ W,
                                             unsigned* __restrict__ s8lo, unsigned* __restrict__ s8hi,
                                             float* __restrict__ Wc,
                                             int* __restrict__ bcnt, const int* __restrict__ dst,
                                             int N, int E, int nbk, int packb, int ablk) {
    __shared__ int lhist[NBKMAX];
    int tid = threadIdx.x;
    int bx = blockIdx.x;

    if (bx < packb) {
        // ---- pack x0 -> fp8 half rows ----
        int t = bx * 256 + tid;
        if (t >= N * 32) return;
        int d = t >> 5, q = t & 31;
        unsigned p = 0u;
        if (q < D / 4) {
            float4 v = *(const float4*)(x0 + (long)d * D + q * 4);
            p = (unsigned)pk8(v.x, v.y) | ((unsigned)pk8(v.z, v.w) << 16);
        }
        if (q < 16) s8lo[(long)d * 16 + q] = p;
        else        s8hi[(long)d * 16 + (q - 16)] = p;
    } else if (bx < packb + ablk) {
        // ---- bucketA: LDS-staged bucket histogram ----
        int base = (bx - packb) * EPB;
        int count = min(EPB, E - base);
        for (int i = tid; i < NBKMAX; i += 256) lhist[i] = 0;
        __syncthreads();
        for (int i = tid; i < count; i += 256) atomicAdd(&lhist[dst[base + i] >> BSHIFT], 1);
        __syncthreads();
        for (int b = tid; b < nbk; b += 256)
            if (lhist[b]) atomicAdd(&bcnt[b], lhist[b]);
    } else {
        // ---- Wc = W2 * W1 (one thread per output element, uniform work) ----
        int t = (bx - packb - ablk) * 256 + tid;
        if (t >= D * D) return;
        int i = t / D, j = t - i * D;
        const float* w2 = W + D * D + (long)i * D;
        float s = 0.f;
        for (int k = 0; k < D; k++) s += w2[k] * W[(long)k * D + j];
        Wc[t] = s;
    }
}

// ---------------- fused: scanB (block 0) | W prepack (blocks 1..14) ----------------
// P[((l*7+nt)*4+kt)*64+lane] = 8 bf16 of M[nt*16+(lane&15)][kt*32+(lane>>4)*8+j],
//   M = W1 (l=0) or Wc (l=1).
__global__ __launch_bounds__(256) void k_scanB_prep(const int* __restrict__ bucket_cnt,
                                                    int* __restrict__ bucket_off,
                                                    int* __restrict__ bucket_cur, int nbk, int E,
                                                    const float* __restrict__ W1,
                                                    const float* __restrict__ Wc,
                                                    unsigned short* __restrict__ P, int wtot) {
    int tid = threadIdx.x;
    if (blockIdx.x == 0) {
        __shared__ int a[NBKMAX], t[256];
        a[tid]       = (tid < nbk) ? bucket_cnt[tid] : 0;
        a[tid + 256] = (tid + 256 < nbk) ? bucket_cnt[tid + 256] : 0;
        __syncthreads();
        scan512_excl(a, t, tid);
        if (tid < nbk)       { bucket_off[tid] = a[tid];             bucket_cur[tid] = a[tid]; }
        if (tid + 256 < nbk) { bucket_off[tid + 256] = a[tid + 256]; bucket_cur[tid + 256] = a[tid + 256]; }
        if (tid == 0) bucket_off[nbk] = E;
    } else {
        int t = (blockIdx.x - 1) * 256 + tid;
        if (t >= wtot) return;
        int lane = t & 63;
        int r = t >> 6;
        int kt = r & 3;
        int r2 = r >> 2;
        int nt = r2 % 7;
        int l  = r2 / 7;
        const float* M = (l == 0) ? W1 : Wc;
        int ng = nt * 16 + (lane & 15);
        int k0 = kt * 32 + (lane >> 4) * 8;
        unsigned short u[8];
#pragma unroll
        for (int j = 0; j < 8; j++) {
            int k = k0 + j;
            u[j] = (ng < D && k < D) ? f2bf(M[(long)ng * D + k]) : (unsigned short)0;
        }
        uint4 o;
        o.x = (unsigned)u[0] | ((unsigned)u[1] << 16);
        o.y = (unsigned)u[2] | ((unsigned)u[3] << 16);
        o.z = (unsigned)u[4] | ((unsigned)u[5] << 16);
        o.w = (unsigned)u[6] | ((unsigned)u[7] << 16);
        *(uint4*)(P + (long)t * 8) = o;
    }
}

// ---------------- Phase C: bucketed edge dump, coalesced writes ----------------
// ebuf entry: (dst & 127) << 16 | src   (requires N <= 65536)
__global__ __launch_bounds__(256) void k_bucketC(const int* __restrict__ src,
                                                 const int* __restrict__ dst,
                                                 int* __restrict__ bucket_cur,
                                                 unsigned* __restrict__ ebuf, int E, int nbk) {
    __shared__ int lhist[NBKMAX], lstart[NBKMAX], runS[NBKMAX], t[256];
    __shared__ unsigned stage[EPB];
    int tid = threadIdx.x;
    int base = blockIdx.x * EPB;
    int count = min(EPB, E - base);

    for (int i = tid; i < NBKMAX; i += 256) lhist[i] = 0;
    __syncthreads();
    for (int i = tid; i < count; i += 256) atomicAdd(&lhist[dst[base + i] >> BSHIFT], 1);
    __syncthreads();
    for (int i = tid; i < NBKMAX; i += 256) lstart[i] = lhist[i];
    __syncthreads();
    scan512_excl(lstart, t, tid);
    for (int b = tid; b < nbk; b += 256) {
        int c = lhist[b];
        runS[b] = c ? atomicAdd(&bucket_cur[b], c) : 0;
    }
    __syncthreads();
    for (int i = tid; i < NBKMAX; i += 256) lhist[i] = 0;
    __syncthreads();
    for (int i = tid; i < count; i += 256) {
        int dv = dst[base + i];
        int sv = src[base + i];
        int b = dv >> BSHIFT;
        int r = atomicAdd(&lhist[b], 1);
        stage[lstart[b] + r] = ((unsigned)(dv & BMASK) << 16) | (unsigned)sv;
    }
    __syncthreads();
    int wave = tid >> 6, lane = tid & 63;
    for (int b = wave; b < nbk; b += 4) {
        int c = lhist[b], ls = lstart[b], rs = runS[b];
        for (int j = lane; j < c; j += 64) ebuf[rs + j] = stage[ls + j];
    }
}

// ---------------- Phase D: per-bucket CSR finalize (coalesced) ----------------
__global__ __launch_bounds__(256) void k_bucketD(const unsigned* __restrict__ ebuf,
                                                 const int* __restrict__ bucket_off,
                                                 int* __restrict__ col, int* __restrict__ rowptr,
                                                 int N, int nbk, int E) {
    __shared__ int lh[BSIZE], ls[BSIZE];
    __shared__ int colStage[DCAP];
    int b = blockIdx.x;
    int tid = threadIdx.x;
    int beg = bucket_off[b], end = bucket_off[b + 1];
    int cnt = end - beg;

    if (tid < BSIZE) lh[tid] = 0;
    __syncthreads();
    for (int i = tid; i < cnt; i += 256) atomicAdd(&lh[ebuf[beg + i] >> 16], 1);
    __syncthreads();
    if (tid < BSIZE) ls[tid] = lh[tid];
    __syncthreads();
    for (int off = 1; off < BSIZE; off <<= 1) {
        int v = (tid >= off && tid < BSIZE) ? ls[tid - off] : 0;
        __syncthreads();
        if (tid < BSIZE) ls[tid] += v;
        __syncthreads();
    }
    if (tid < BSIZE) ls[tid] -= lh[tid];
    __syncthreads();
    int d0 = b * BSIZE;
    if (tid < BSIZE && d0 + tid < N) rowptr[d0 + tid] = beg + ls[tid];
    if (b == nbk - 1 && tid == 0) rowptr[N] = E;
    if (tid < BSIZE) lh[tid] = 0;
    __syncthreads();
    if (cnt <= DCAP) {
        for (int i = tid; i < cnt; i += 256) {
            unsigned p = ebuf[beg + i];
            int r = p >> 16, s = (int)(p & 0xffffu);
            int k = atomicAdd(&lh[r], 1);
            colStage[ls[r] + k] = s;
        }
        __syncthreads();
        for (int i = tid; i < cnt; i += 256) col[beg + i] = colStage[i];
    } else {
        for (int i = tid; i < cnt; i += 256) {
            unsigned p = ebuf[beg + i];
            int r = p >> 16, s = (int)(p & 0xffffu);
            int k = atomicAdd(&lh[r], 1);
            col[beg + ls[r] + k] = s;
        }
    }
}

// ---------------- half-row SpMM on fp8: o[h] = (g[d] + sum g[src]) / deg ----------------
// One wave per dst node; 4 groups of 16 lanes. Each group gathers a DIFFERENT src half-row
// per vmem instruction (16 lanes x dword = 64 B). Half array = 3.2 MB -> L2-resident.
// Lane (g, j=lane&15) accumulates dims h*64+4j..4j+3; cross-group shfl_xor reduce at end.
// gh: fp8 e4m3 half rows, 64 B each (uint q = dims h*64+4q..4q+3).
// self16 (optional): FULL bf16 rows; self term read at half h (higher precision, layer 2).
// Outputs: o16 full bf16 rows, half h written by group 0; o8h fp8 half rows by group 1.
__global__ __launch_bounds__(256) void k_spmm_h(const unsigned* __restrict__ gh,
                                                const int* __restrict__ rowptr,
                                                const int* __restrict__ col,
                                                const unsigned* __restrict__ self16,
                                                unsigned* __restrict__ o8h,
                                                unsigned* __restrict__ o16,
                                                int h, int N) {
    int wave = threadIdx.x >> 6;
    int lane = threadIdx.x & 63;
    int g = lane >> 4;
    int j = lane & 15;
    int d = blockIdx.x * 4 + wave;
    if (d >= N) return;

    int b0 = __builtin_amdgcn_readfirstlane(rowptr[d]);
    int e0 = __builtin_amdgcn_readfirstlane(rowptr[d + 1]);

    float a0 = 0.f, a1 = 0.f, a2 = 0.f, a3 = 0.f;
    // self term: group 0 only (cross-group reduce then counts it exactly once)
    if (g == 0) {
        if (self16) {
            uint2 sv = *((const uint2*)(self16 + (long)d * 64 + h * 32) + j);
            a0 = bflo(sv.x); a1 = bfhi(sv.x);
            a2 = bflo(sv.y); a3 = bfhi(sv.y);
        } else {
            unsigned sv = gh[(long)d * 16 + j];
            acc4(a0, a1, a2, a3, sv, 1.f);
        }
    }

    for (int win = b0; win < e0; win += 64) {
        int m = e0 - win;
        if (m > 64) m = 64;
        int c = col[win + lane];  // lanes >= m hold garbage; never shfl'd from
        int t = 0;
        for (; t + 16 <= m; t += 16) {
            int sa = __shfl(c, t + g);
            int sb = __shfl(c, t + 4 + g);
            int sc = __shfl(c, t + 8 + g);
            int sd = __shfl(c, t + 12 + g);
            unsigned va = gh[(long)sa * 16 + j];
            unsigned vb = gh[(long)sb * 16 + j];
            unsigned vc = gh[(long)sc * 16 + j];
            unsigned vd = gh[(long)sd * 16 + j];
            acc4(a0, a1, a2, a3, va, 1.f);
            acc4(a0, a1, a2, a3, vb, 1.f);
            acc4(a0, a1, a2, a3, vc, 1.f);
            acc4(a0, a1, a2, a3, vd, 1.f);
        }
        for (; t + 8 <= m; t += 8) {
            int sa = __shfl(c, t + g);
            int sb = __shfl(c, t + 4 + g);
            unsigned va = gh[(long)sa * 16 + j];
            unsigned vb = gh[(long)sb * 16 + j];
            acc4(a0, a1, a2, a3, va, 1.f);
            acc4(a0, a1, a2, a3, vb, 1.f);
        }
        for (; t < m; t += 4) {
            int rem = m - t;                      // 1..7 on first tail iter, then 1..3
            int idx = t + ((g < rem) ? g : 0);    // clamp keeps shfl source < m (valid)
            int sa = __shfl(c, idx);
            float w = (g < rem) ? 1.f : 0.f;
            unsigned va = gh[(long)sa * 16 + j];
            acc4(a0, a1, a2, a3, va, w);
        }
    }

    // cross-group butterfly reduce (lane bits 4,5)
    a0 += __shfl_xor(a0, 16); a0 += __shfl_xor(a0, 32);
    a1 += __shfl_xor(a1, 16); a1 += __shfl_xor(a1, 32);
    a2 += __shfl_xor(a2, 16); a2 += __shfl_xor(a2, 32);
    a3 += __shfl_xor(a3, 16); a3 += __shfl_xor(a3, 32);

    float dinv = 1.f / (float)(e0 - b0 + 1);
    float r0 = a0 * dinv, r1 = a1 * dinv, r2 = a2 * dinv, r3 = a3 * dinv;

    // dims >= 100 are zero end-to-end (inputs zero-padded), so writes stay zero
    if (g == 0) {
        uint2 o;
        o.x = (unsigned)f2bf(r0) | ((unsigned)f2bf(r1) << 16);
        o.y = (unsigned)f2bf(r2) | ((unsigned)f2bf(r3) << 16);
        *((uint2*)(o16 + (long)d * 64 + h * 32) + j) = o;
    }
    if (o8h && g == 1) {
        o8h[(long)d * 16 + j] = (unsigned)pk8(r0, r1) | ((unsigned)pk8(r2, r3) << 16);
    }
}

// ---------------- fused epilogue: x1=u*W1^T, x2=v*Wc^T, norms, out ----------------
__global__ __launch_bounds__(256) void k_epi(const unsigned short* __restrict__ u16,
                                             const unsigned short* __restrict__ v16,
                                             const unsigned short* __restrict__ P,  // W1 then Wc frags
                                             const float* __restrict__ x0,
                                             float invlp1, float* __restrict__ out, int N) {
    int wave = threadIdx.x >> 6;
    int lane = threadIdx.x & 63;
    int quad = lane >> 4;
    int l16  = lane & 15;
    int rowbase = (blockIdx.x * 4 + wave) * 16;
    if (rowbase >= N) return;
    int arow = rowbase + l16;
    if (arow >= N) arow = N - 1;

    bf8v aU[4], aV[4];
    const unsigned short* ur = u16 + (long)arow * YSTRIDE;
    const unsigned short* vr = v16 + (long)arow * YSTRIDE;
#pragma unroll
    for (int kt = 0; kt < 4; kt++) {
        int k0 = kt * 32 + quad * 8;
        union { bf8v v; uint4 u; } a, b;
        a.u = *(const uint4*)(ur + k0);
        b.u = *(const uint4*)(vr + k0);
        aU[kt] = a.v;
        aV[kt] = b.v;
    }

    f4v accU[7], accV[7];
#pragma unroll
    for (int nt = 0; nt < 7; nt++) { accU[nt] = (f4v){0,0,0,0}; accV[nt] = (f4v){0,0,0,0}; }

    const uint4* bp = (const uint4*)P;
#pragma unroll
    for (int nt = 0; nt < 7; nt++) {
#pragma unroll
        for (int kt = 0; kt < 4; kt++) {
            union { uint4 u; bf8v v; } b1, b2;
            b1.u = bp[(nt * 4 + kt) * 64 + lane];
            b2.u = bp[(28 + nt * 4 + kt) * 64 + lane];
            accU[nt] = __builtin_amdgcn_mfma_f32_16x16x32_bf16(aU[kt], b1.v, accU[nt], 0, 0, 0);
            accV[nt] = __builtin_amdgcn_mfma_f32_16x16x32_bf16(aV[kt], b2.v, accV[nt], 0, 0, 0);
        }
    }

    float sU[4], sV[4];
#pragma unroll
    for (int i = 0; i < 4; i++) {
        float nu = 0.f, nv = 0.f;
#pragma unroll
        for (int nt = 0; nt < 7; nt++) {
            nu += accU[nt][i] * accU[nt][i];
            nv += accV[nt][i] * accV[nt][i];
        }
#pragma unroll
        for (int m = 1; m < 16; m <<= 1) {
            nu += __shfl_xor(nu, m);
            nv += __shfl_xor(nv, m);
        }
        sU[i] = invlp1 / fmaxf(sqrtf(nu), 1e-12f);
        sV[i] = invlp1 / fmaxf(sqrtf(nv), 1e-12f);
    }

#pragma unroll
    for (int nt = 0; nt < 7; nt++) {
        int cc = nt * 16 + l16;
        if (cc < D) {
#pragma unroll
            for (int i = 0; i < 4; i++) {
                int rr = rowbase + quad * 4 + i;
                if (rr < N) {
                    long idx = (long)rr * D + cc;
                    out[idx] = x0[idx] * invlp1 + accU[nt][i] * sU[i] + accV[nt][i] * sV[i];
                }
            }
        }
    }
}

// ---------------- launcher ----------------

extern "C" void kernel_launch(void* const* d_in, const int* in_sizes, int n_in,
                              void* d_out, int out_size, void* d_ws, size_t ws_size,
                              hipStream_t stream) {
    const float* features = (const float*)d_in[0];
    const float* W        = (const float*)d_in[1];
    const int*   src      = (const int*)d_in[2];
    const int*   dstv     = (const int*)d_in[3];

    int N = in_sizes[0] / D;            // 50000
    int E = in_sizes[2];                // 800000
    int L = in_sizes[1] / (D * D);      // 2 (composition assumes L==2)
    float invlp1 = 1.f / (float)(L + 1);
    int NBK = (N + BSIZE - 1) >> BSHIFT;

    char*  ws  = (char*)d_ws;
    size_t off = 0;
    auto alloc = [&](size_t bytes) -> void* {
        void* p = (void*)(ws + off);
        off += (bytes + 255) & ~(size_t)255;
        return p;
    };
    unsigned*       s8lo   = (unsigned*)alloc((size_t)N * 16 * sizeof(unsigned));  // fp8 half rows (64 B)
    unsigned*       s8hi   = (unsigned*)alloc((size_t)N * 16 * sizeof(unsigned));
    unsigned*       u8lo   = (unsigned*)alloc((size_t)N * 16 * sizeof(unsigned));
    unsigned*       u8hi   = (unsigned*)alloc((size_t)N * 16 * sizeof(unsigned));
    unsigned*       u16    = (unsigned*)alloc((size_t)N * 64 * sizeof(unsigned));  // bf16 rows (256 B)
    unsigned*       v16    = (unsigned*)alloc((size_t)N * 64 * sizeof(unsigned));  // bf16 rows (256 B)
    float*          Wc     = (float*)alloc((size_t)D * D * sizeof(float));
    unsigned short* wpack  = (unsigned short*)alloc((size_t)2 * 7 * 4 * 64 * 8 * sizeof(unsigned short));
    unsigned*       ebuf   = (unsigned*)alloc((size_t)E * sizeof(unsigned));
    int*            colb   = (int*)alloc((size_t)E * sizeof(int));
    int*            rowptr = (int*)alloc((size_t)(N + 1) * sizeof(int));
    int*            bcnt   = (int*)alloc((size_t)NBKMAX * sizeof(int));
    int*            boff   = (int*)alloc((size_t)(NBKMAX + 1) * sizeof(int));
    int*            bcur   = (int*)alloc((size_t)NBKMAX * sizeof(int));

    int nebk  = (E + EPB - 1) / EPB;
    int wtot  = 2 * 7 * 4 * 64;                 // 3584 fragment rows
    int packb = (N * 32 + 255) / 256;
    int wcb   = (D * D + 255) / 256;
    int prepb = (wtot + 255) / 256;

    hipMemsetAsync(bcnt, 0, (size_t)NBK * sizeof(int), stream);
    k_pre<<<packb + nebk + wcb, 256, 0, stream>>>(features, W, s8lo, s8hi, Wc, bcnt, dstv,
                                                  N, E, NBK, packb, nebk);
    k_scanB_prep<<<1 + prepb, 256, 0, stream>>>(bcnt, boff, bcur, NBK, E, W, Wc, wpack, wtot);
    k_bucketC<<<nebk, 256, 0, stream>>>(src, dstv, bcur, ebuf, E, NBK);
    k_bucketD<<<NBK, 256, 0, stream>>>(ebuf, boff, colb, rowptr, N, NBK, E);

    int spmmblocks = (N + 3) / 4;  // 4 waves x 1 node per block
    // order u_lo -> v_lo -> u_hi -> v_hi: v_h gathers u8h written by the immediately
    // preceding pass (hot in L2); each sub-pass's gather footprint is 3.2 MB (L2-resident)
    k_spmm_h<<<spmmblocks, 256, 0, stream>>>(s8lo, rowptr, colb, (const unsigned*)nullptr,
                                             u8lo, u16, 0, N);
    k_spmm_h<<<spmmblocks, 256, 0, stream>>>(u8lo, rowptr, colb, u16,
                                             (unsigned*)nullptr, v16, 0, N);
    k_spmm_h<<<spmmblocks, 256, 0, stream>>>(s8hi, rowptr, colb, (const unsigned*)nullptr,
                                             u8hi, u16, 1, N);
    k_spmm_h<<<spmmblocks, 256, 0, stream>>>(u8hi, rowptr, colb, u16,
                                             (unsigned*)nullptr, v16, 1, N);

    int nrowtiles = (N + 15) / 16;
    int epiblocks = (nrowtiles + 3) / 4;
    k_epi<<<epiblocks, 256, 0, stream>>>((const unsigned short*)u16, (const unsigned short*)v16,
                                         wpack, features, invlp1, (float*)d_out, N);
}

// Round 4
// 200.526 us; speedup vs baseline: 1.1916x; 1.1916x over previous
//
#include <hip/hip_runtime.h>

#define D 100
#define YSTRIDE 128   // bf16 row stride in elements (256 B = 64 uints)
#define BSHIFT 7      // 128 dst nodes per bucket
#define BSIZE 128
#define BMASK 127
#define NBKMAX 512    // supports N <= 65536
#define EPB 2048      // edges per block in bucket passes
#define DCAP 4096     // per-bucket staging capacity in phase D

typedef __attribute__((ext_vector_type(8))) short bf8v;
typedef __attribute__((ext_vector_type(4))) float f4v;

__device__ inline unsigned short f2bf(float f) {
    unsigned u = __float_as_uint(f);
    return (unsigned short)((u + 0x7fffu + ((u >> 16) & 1u)) >> 16);  // RNE
}
__device__ inline float bflo(unsigned v) { return __uint_as_float(v << 16); }
__device__ inline float bfhi(unsigned v) { return __uint_as_float(v & 0xffff0000u); }
// fp8 e4m3 (OCP on gfx950) helpers
__device__ inline unsigned short pk8(float a, float b) {
    return (unsigned short)(__builtin_amdgcn_cvt_pk_fp8_f32(a, b, 0, false) & 0xffff);
}
__device__ inline float up8lo(unsigned v) { return __builtin_amdgcn_cvt_f32_fp8((int)v, 0); }
__device__ inline float up8hi(unsigned v) { return __builtin_amdgcn_cvt_f32_fp8((int)v, 1); }

// accumulate 8 fp8 values (bytes of a uint2) into acc[0..8), weighted
__device__ inline void acc8(float* acc, uint2 v, float w) {
    acc[0] = fmaf(__builtin_amdgcn_cvt_f32_fp8((int)v.x, 0), w, acc[0]);
    acc[1] = fmaf(__builtin_amdgcn_cvt_f32_fp8((int)v.x, 1), w, acc[1]);
    acc[2] = fmaf(__builtin_amdgcn_cvt_f32_fp8((int)v.x, 2), w, acc[2]);
    acc[3] = fmaf(__builtin_amdgcn_cvt_f32_fp8((int)v.x, 3), w, acc[3]);
    acc[4] = fmaf(__builtin_amdgcn_cvt_f32_fp8((int)v.y, 0), w, acc[4]);
    acc[5] = fmaf(__builtin_amdgcn_cvt_f32_fp8((int)v.y, 1), w, acc[5]);
    acc[6] = fmaf(__builtin_amdgcn_cvt_f32_fp8((int)v.y, 2), w, acc[6]);
    acc[7] = fmaf(__builtin_amdgcn_cvt_f32_fp8((int)v.y, 3), w, acc[7]);
}

// exclusive scan of a[0..512) in LDS, t[256] scratch; 256 threads
__device__ inline void scan512_excl(int* a, int* t, int tid) {
    int v0 = a[2 * tid], v1 = a[2 * tid + 1];
    t[tid] = v0 + v1;
    __syncthreads();
    for (int off = 1; off < 256; off <<= 1) {
        int u = (tid >= off) ? t[tid - off] : 0;
        __syncthreads();
        t[tid] += u;
        __syncthreads();
    }
    int base = (tid ? t[tid - 1] : 0);
    a[2 * tid]     = base;
    a[2 * tid + 1] = base + v0;
    __syncthreads();
}

// ---------------- fused preamble: pack x0->fp8 rows | per-block bucket hist | Wc=W2*W1 ----
// NO global atomics: each edge-block writes its full histogram row hist[blk][bucket]
// (coalesced); the column scan (next kernel) derives totals and per-block offsets.
__global__ __launch_bounds__(256) void k_pre(const float* __restrict__ x0, const float* __restrict__ W,
                                             unsigned* __restrict__ s8, float* __restrict__ Wc,
                                             int* __restrict__ hist, const int* __restrict__ dst,
                                             int N, int E, int nbk, int packb, int ablk) {
    __shared__ int lhist[NBKMAX];
    int tid = threadIdx.x;
    int bx = blockIdx.x;

    if (bx < packb) {
        // ---- pack x0 -> fp8 full rows (128 B each) ----
        int t = bx * 256 + tid;
        if (t >= N * 32) return;
        int d = t >> 5, q = t & 31;
        unsigned p = 0u;
        if (q < D / 4) {
            float4 v = *(const float4*)(x0 + (long)d * D + q * 4);
            p = (unsigned)pk8(v.x, v.y) | ((unsigned)pk8(v.z, v.w) << 16);
        }
        s8[t] = p;
    } else if (bx < packb + ablk) {
        // ---- per-block bucket histogram (LDS atomics only) ----
        int blk = bx - packb;
        int base = blk * EPB;
        int count = min(EPB, E - base);
        for (int i = tid; i < NBKMAX; i += 256) lhist[i] = 0;
        __syncthreads();
        for (int i = tid; i < count; i += 256) atomicAdd(&lhist[dst[base + i] >> BSHIFT], 1);
        __syncthreads();
        for (int b = tid; b < NBKMAX; b += 256) hist[(long)blk * NBKMAX + b] = lhist[b];
    } else {
        // ---- Wc = W2 * W1 (one thread per output element, uniform work) ----
        int t = (bx - packb - ablk) * 256 + tid;
        if (t >= D * D) return;
        int i = t / D, j = t - i * D;
        const float* w2 = W + D * D + (long)i * D;
        float s = 0.f;
        for (int k = 0; k < D; k++) s += w2[k] * W[(long)k * D + j];
        Wc[t] = s;
    }
}

// ---------------- fused: column scan over blocks (blocks 0..nbk-1) | W prepack ----------------
// Block b: pref[blk][b] = # edges of bucket b in edge-blocks < blk; bcnt[b] = total.
// Requires nebk <= 511 (E <= 511*EPB). Prepack blocks follow.
__global__ __launch_bounds__(256) void k_colscan_prep(const int* __restrict__ hist,
                                                      int* __restrict__ pref, int* __restrict__ bcnt,
                                                      int nebk, int nbk,
                                                      const float* __restrict__ W1,
                                                      const float* __restrict__ Wc,
                                                      unsigned short* __restrict__ P, int wtot) {
    int tid = threadIdx.x;
    if ((int)blockIdx.x < nbk) {
        int b = blockIdx.x;
        __shared__ int a[NBKMAX], t[256];
        int i0 = tid, i1 = tid + 256;
        a[i0] = (i0 < nebk) ? hist[(long)i0 * NBKMAX + b] : 0;
        a[i1] = (i1 < nebk) ? hist[(long)i1 * NBKMAX + b] : 0;
        __syncthreads();
        scan512_excl(a, t, tid);
        if (i0 < nebk) pref[(long)i0 * NBKMAX + b] = a[i0];
        if (i1 < nebk) pref[(long)i1 * NBKMAX + b] = a[i1];
        if (tid == 0) bcnt[b] = a[nebk];  // nebk <= 511: entries beyond are 0
    } else {
        int t2 = ((int)blockIdx.x - nbk) * 256 + tid;
        if (t2 >= wtot) return;
        int lane = t2 & 63;
        int r = t2 >> 6;
        int kt = r & 3;
        int r2 = r >> 2;
        int nt = r2 % 7;
        int l  = r2 / 7;
        const float* M = (l == 0) ? W1 : Wc;
        int ng = nt * 16 + (lane & 15);
        int k0 = kt * 32 + (lane >> 4) * 8;
        unsigned short u[8];
#pragma unroll
        for (int j = 0; j < 8; j++) {
            int k = k0 + j;
            u[j] = (ng < D && k < D) ? f2bf(M[(long)ng * D + k]) : (unsigned short)0;
        }
        uint4 o;
        o.x = (unsigned)u[0] | ((unsigned)u[1] << 16);
        o.y = (unsigned)u[2] | ((unsigned)u[3] << 16);
        o.z = (unsigned)u[4] | ((unsigned)u[5] << 16);
        o.w = (unsigned)u[6] | ((unsigned)u[7] << 16);
        *(uint4*)(P + (long)t2 * 8) = o;
    }
}

// ---------------- scanB: bucket totals -> global bucket offsets (1 block) ----------------
__global__ __launch_bounds__(256) void k_scanB(const int* __restrict__ bcnt,
                                               int* __restrict__ boff, int nbk, int E) {
    __shared__ int a[NBKMAX], t[256];
    int tid = threadIdx.x;
    a[tid]       = (tid < nbk) ? bcnt[tid] : 0;
    a[tid + 256] = (tid + 256 < nbk) ? bcnt[tid + 256] : 0;
    __syncthreads();
    scan512_excl(a, t, tid);
    if (tid < nbk)       boff[tid] = a[tid];
    if (tid + 256 < nbk) boff[tid + 256] = a[tid + 256];
    if (tid == 0) boff[nbk] = E;
}

// ---------------- Phase C: bucketed edge dump, deterministic offsets, no atomics ----------
// ebuf entry: (dst & 127) << 16 | src   (requires N <= 65536)
__global__ __launch_bounds__(256) void k_bucketC(const int* __restrict__ src,
                                                 const int* __restrict__ dst,
                                                 const int* __restrict__ boff,
                                                 const int* __restrict__ pref,
                                                 unsigned* __restrict__ ebuf, int E, int nbk) {
    __shared__ int lhist[NBKMAX], lstart[NBKMAX], runS[NBKMAX], t[256];
    __shared__ unsigned stage[EPB];
    int tid = threadIdx.x;
    int base = blockIdx.x * EPB;
    int count = min(EPB, E - base);

    for (int i = tid; i < NBKMAX; i += 256) lhist[i] = 0;
    __syncthreads();
    for (int i = tid; i < count; i += 256) atomicAdd(&lhist[dst[base + i] >> BSHIFT], 1);
    __syncthreads();
    for (int i = tid; i < NBKMAX; i += 256) lstart[i] = lhist[i];
    __syncthreads();
    scan512_excl(lstart, t, tid);
    // global landing offset for this block's slice of each bucket: no atomics
    for (int b = tid; b < nbk; b += 256)
        runS[b] = boff[b] + pref[(long)blockIdx.x * NBKMAX + b];
    __syncthreads();
    for (int i = tid; i < NBKMAX; i += 256) lhist[i] = 0;
    __syncthreads();
    for (int i = tid; i < count; i += 256) {
        int dv = dst[base + i];
        int sv = src[base + i];
        int b = dv >> BSHIFT;
        int r = atomicAdd(&lhist[b], 1);
        stage[lstart[b] + r] = ((unsigned)(dv & BMASK) << 16) | (unsigned)sv;
    }
    __syncthreads();
    int wave = tid >> 6, lane = tid & 63;
    for (int b = wave; b < nbk; b += 4) {
        int c = lhist[b], ls = lstart[b], rs = runS[b];
        for (int j = lane; j < c; j += 64) ebuf[rs + j] = stage[ls + j];
    }
}

// ---------------- Phase D: per-bucket CSR finalize (coalesced) ----------------
__global__ __launch_bounds__(256) void k_bucketD(const unsigned* __restrict__ ebuf,
                                                 const int* __restrict__ bucket_off,
                                                 int* __restrict__ col, int* __restrict__ rowptr,
                                                 int N, int nbk, int E) {
    __shared__ int lh[BSIZE], ls[BSIZE];
    __shared__ int colStage[DCAP];
    int b = blockIdx.x;
    int tid = threadIdx.x;
    int beg = bucket_off[b], end = bucket_off[b + 1];
    int cnt = end - beg;

    if (tid < BSIZE) lh[tid] = 0;
    __syncthreads();
    for (int i = tid; i < cnt; i += 256) atomicAdd(&lh[ebuf[beg + i] >> 16], 1);
    __syncthreads();
    if (tid < BSIZE) ls[tid] = lh[tid];
    __syncthreads();
    for (int off = 1; off < BSIZE; off <<= 1) {
        int v = (tid >= off && tid < BSIZE) ? ls[tid - off] : 0;
        __syncthreads();
        if (tid < BSIZE) ls[tid] += v;
        __syncthreads();
    }
    if (tid < BSIZE) ls[tid] -= lh[tid];
    __syncthreads();
    int d0 = b * BSIZE;
    if (tid < BSIZE && d0 + tid < N) rowptr[d0 + tid] = beg + ls[tid];
    if (b == nbk - 1 && tid == 0) rowptr[N] = E;
    if (tid < BSIZE) lh[tid] = 0;
    __syncthreads();
    if (cnt <= DCAP) {
        for (int i = tid; i < cnt; i += 256) {
            unsigned p = ebuf[beg + i];
            int r = p >> 16, s = (int)(p & 0xffffu);
            int k = atomicAdd(&lh[r], 1);
            colStage[ls[r] + k] = s;
        }
        __syncthreads();
        for (int i = tid; i < cnt; i += 256) col[beg + i] = colStage[i];
    } else {
        for (int i = tid; i < cnt; i += 256) {
            unsigned p = ebuf[beg + i];
            int r = p >> 16, s = (int)(p & 0xffffu);
            int k = atomicAdd(&lh[r], 1);
            col[beg + ls[r] + k] = s;
        }
    }
}

// ---------------- pure SpMM on fp8 rows: o = (g[d] + sum g[src]) / deg ----------------
// One wave per dst node. 4 groups of 16 lanes; each group gathers a DIFFERENT src row
// per vmem instruction (16 lanes x dwordx2 = 128 B row).
// Lane (g, j=lane&15) accumulates dims 8j..8j+7; cross-group shfl_xor reduce at end.
// g8: fp8 e4m3 rows, 128 B each, byte k = dim k (linear).
// self16 (optional): bf16 rows for the self term (higher precision).
// Outputs: o16 bf16 rows always (group 0 writes); o8 fp8 rows if write8 (group 1 writes).
__global__ __launch_bounds__(256) void k_spmm(const unsigned short* __restrict__ g8,
                                              const int* __restrict__ rowptr,
                                              const int* __restrict__ col,
                                              const unsigned* __restrict__ self16,
                                              unsigned short* __restrict__ o8,
                                              unsigned* __restrict__ o16,
                                              int write8, int N) {
    int wave = threadIdx.x >> 6;
    int lane = threadIdx.x & 63;
    int g = lane >> 4;
    int j = lane & 15;
    int d = blockIdx.x * 4 + wave;
    if (d >= N) return;

    int b0 = __builtin_amdgcn_readfirstlane(rowptr[d]);
    int e0 = __builtin_amdgcn_readfirstlane(rowptr[d + 1]);

    float acc[8];
    // self term: group 0 only (cross-group reduce then counts it exactly once)
    if (g == 0) {
        if (self16) {
            uint4 sv = *((const uint4*)(self16 + (long)d * 64) + j);
            acc[0] = bflo(sv.x); acc[1] = bfhi(sv.x);
            acc[2] = bflo(sv.y); acc[3] = bfhi(sv.y);
            acc[4] = bflo(sv.z); acc[5] = bfhi(sv.z);
            acc[6] = bflo(sv.w); acc[7] = bfhi(sv.w);
        } else {
            uint2 sv = *(const uint2*)(g8 + (long)d * 64 + j * 4);
#pragma unroll
            for (int k = 0; k < 8; k++) acc[k] = 0.f;
            acc8(acc, sv, 1.f);
        }
    } else {
#pragma unroll
        for (int k = 0; k < 8; k++) acc[k] = 0.f;
    }

    for (int win = b0; win < e0; win += 64) {
        int m = e0 - win;
        if (m > 64) m = 64;
        int c = col[win + lane];  // lanes >= m hold garbage; never shfl'd from
        int t = 0;
        for (; t + 8 <= m; t += 8) {
            int sa = __shfl(c, t + g);
            int sb = __shfl(c, t + 4 + g);
            uint2 va = *(const uint2*)(g8 + (long)sa * 64 + j * 4);
            uint2 vb = *(const uint2*)(g8 + (long)sb * 64 + j * 4);
            acc8(acc, va, 1.f);
            acc8(acc, vb, 1.f);
        }
        for (; t < m; t += 4) {
            int rem = m - t;                      // 1..7 on first tail iter, then 1..3
            int idx = t + ((g < rem) ? g : 0);    // clamp keeps shfl source < m (valid)
            int sa = __shfl(c, idx);
            float w = (g < rem) ? 1.f : 0.f;
            uint2 va = *(const uint2*)(g8 + (long)sa * 64 + j * 4);
            acc8(acc, va, w);
        }
    }

    // cross-group butterfly reduce (lane bits 4,5)
#pragma unroll
    for (int k = 0; k < 8; k++) {
        acc[k] += __shfl_xor(acc[k], 16);
        acc[k] += __shfl_xor(acc[k], 32);
    }

    float dinv = 1.f / (float)(e0 - b0 + 1);
    float r[8];
#pragma unroll
    for (int k = 0; k < 8; k++) r[k] = acc[k] * dinv;

    // dims >= 100 are zero end-to-end (inputs zero-padded), so writes stay zero
    if (g == 0) {
        uint4 o;
        o.x = (unsigned)f2bf(r[0]) | ((unsigned)f2bf(r[1]) << 16);
        o.y = (unsigned)f2bf(r[2]) | ((unsigned)f2bf(r[3]) << 16);
        o.z = (unsigned)f2bf(r[4]) | ((unsigned)f2bf(r[5]) << 16);
        o.w = (unsigned)f2bf(r[6]) | ((unsigned)f2bf(r[7]) << 16);
        *((uint4*)(o16 + (long)d * 64) + j) = o;
    }
    if (write8 && g == 1) {
        uint2 p;
        p.x = (unsigned)pk8(r[0], r[1]) | ((unsigned)pk8(r[2], r[3]) << 16);
        p.y = (unsigned)pk8(r[4], r[5]) | ((unsigned)pk8(r[6], r[7]) << 16);
        *((uint2*)((unsigned*)o8 + (long)d * 32) + j) = p;
    }
}

// ---------------- fused epilogue: x1=u*W1^T, x2=v*Wc^T, norms, out ----------------
__global__ __launch_bounds__(256) void k_epi(const unsigned short* __restrict__ u16,
                                             const unsigned short* __restrict__ v16,
                                             const unsigned short* __restrict__ P,  // W1 then Wc frags
                                             const float* __restrict__ x0,
                                             float invlp1, float* __restrict__ out, int N) {
    int wave = threadIdx.x >> 6;
    int lane = threadIdx.x & 63;
    int quad = lane >> 4;
    int l16  = lane & 15;
    int rowbase = (blockIdx.x * 4 + wave) * 16;
    if (rowbase >= N) return;
    int arow = rowbase + l16;
    if (arow >= N) arow = N - 1;

    bf8v aU[4], aV[4];
    const unsigned short* ur = u16 + (long)arow * YSTRIDE;
    const unsigned short* vr = v16 + (long)arow * YSTRIDE;
#pragma unroll
    for (int kt = 0; kt < 4; kt++) {
        int k0 = kt * 32 + quad * 8;
        union { bf8v v; uint4 u; } a, b;
        a.u = *(const uint4*)(ur + k0);
        b.u = *(const uint4*)(vr + k0);
        aU[kt] = a.v;
        aV[kt] = b.v;
    }

    f4v accU[7], accV[7];
#pragma unroll
    for (int nt = 0; nt < 7; nt++) { accU[nt] = (f4v){0,0,0,0}; accV[nt] = (f4v){0,0,0,0}; }

    const uint4* bp = (const uint4*)P;
#pragma unroll
    for (int nt = 0; nt < 7; nt++) {
#pragma unroll
        for (int kt = 0; kt < 4; kt++) {
            union { uint4 u; bf8v v; } b1, b2;
            b1.u = bp[(nt * 4 + kt) * 64 + lane];
            b2.u = bp[(28 + nt * 4 + kt) * 64 + lane];
            accU[nt] = __builtin_amdgcn_mfma_f32_16x16x32_bf16(aU[kt], b1.v, accU[nt], 0, 0, 0);
            accV[nt] = __builtin_amdgcn_mfma_f32_16x16x32_bf16(aV[kt], b2.v, accV[nt], 0, 0, 0);
        }
    }

    float sU[4], sV[4];
#pragma unroll
    for (int i = 0; i < 4; i++) {
        float nu = 0.f, nv = 0.f;
#pragma unroll
        for (int nt = 0; nt < 7; nt++) {
            nu += accU[nt][i] * accU[nt][i];
            nv += accV[nt][i] * accV[nt][i];
        }
#pragma unroll
        for (int m = 1; m < 16; m <<= 1) {
            nu += __shfl_xor(nu, m);
            nv += __shfl_xor(nv, m);
        }
        sU[i] = invlp1 / fmaxf(sqrtf(nu), 1e-12f);
        sV[i] = invlp1 / fmaxf(sqrtf(nv), 1e-12f);
    }

#pragma unroll
    for (int nt = 0; nt < 7; nt++) {
        int cc = nt * 16 + l16;
        if (cc < D) {
#pragma unroll
            for (int i = 0; i < 4; i++) {
                int rr = rowbase + quad * 4 + i;
                if (rr < N) {
                    long idx = (long)rr * D + cc;
                    out[idx] = x0[idx] * invlp1 + accU[nt][i] * sU[i] + accV[nt][i] * sV[i];
                }
            }
        }
    }
}

// ---------------- launcher ----------------

extern "C" void kernel_launch(void* const* d_in, const int* in_sizes, int n_in,
                              void* d_out, int out_size, void* d_ws, size_t ws_size,
                              hipStream_t stream) {
    const float* features = (const float*)d_in[0];
    const float* W        = (const float*)d_in[1];
    const int*   src      = (const int*)d_in[2];
    const int*   dstv     = (const int*)d_in[3];

    int N = in_sizes[0] / D;            // 50000
    int E = in_sizes[2];                // 800000
    int L = in_sizes[1] / (D * D);      // 2 (composition assumes L==2)
    float invlp1 = 1.f / (float)(L + 1);
    int NBK = (N + BSIZE - 1) >> BSHIFT;
    int nebk = (E + EPB - 1) / EPB;     // 391 (must be <= 511 for the column scan)

    char*  ws  = (char*)d_ws;
    size_t off = 0;
    auto alloc = [&](size_t bytes) -> void* {
        void* p = (void*)(ws + off);
        off += (bytes + 255) & ~(size_t)255;
        return p;
    };
    unsigned*       s8     = (unsigned*)alloc((size_t)N * 32 * sizeof(unsigned));  // fp8 rows (128 B)
    unsigned*       u8     = (unsigned*)alloc((size_t)N * 32 * sizeof(unsigned));  // fp8 rows (128 B)
    unsigned*       u16    = (unsigned*)alloc((size_t)N * 64 * sizeof(unsigned));  // bf16 rows (256 B)
    unsigned*       v16    = (unsigned*)alloc((size_t)N * 64 * sizeof(unsigned));  // bf16 rows (256 B)
    float*          Wc     = (float*)alloc((size_t)D * D * sizeof(float));
    unsigned short* wpack  = (unsigned short*)alloc((size_t)2 * 7 * 4 * 64 * 8 * sizeof(unsigned short));
    unsigned*       ebuf   = (unsigned*)alloc((size_t)E * sizeof(unsigned));
    int*            colb   = (int*)alloc((size_t)E * sizeof(int));
    int*            rowptr = (int*)alloc((size_t)(N + 1) * sizeof(int));
    int*            hist   = (int*)alloc((size_t)nebk * NBKMAX * sizeof(int));     // per-block hist
    int*            pref   = (int*)alloc((size_t)nebk * NBKMAX * sizeof(int));     // col-scanned
    int*            bcnt   = (int*)alloc((size_t)NBKMAX * sizeof(int));
    int*            boff   = (int*)alloc((size_t)(NBKMAX + 1) * sizeof(int));

    int wtot  = 2 * 7 * 4 * 64;                 // 3584 fragment rows
    int packb = (N * 32 + 255) / 256;
    int wcb   = (D * D + 255) / 256;
    int prepb = (wtot + 255) / 256;

    k_pre<<<packb + nebk + wcb, 256, 0, stream>>>(features, W, s8, Wc, hist, dstv,
                                                  N, E, NBK, packb, nebk);
    k_colscan_prep<<<NBK + prepb, 256, 0, stream>>>(hist, pref, bcnt, nebk, NBK,
                                                    W, Wc, wpack, wtot);
    k_scanB<<<1, 256, 0, stream>>>(bcnt, boff, NBK, E);
    k_bucketC<<<nebk, 256, 0, stream>>>(src, dstv, boff, pref, ebuf, E, NBK);
    k_bucketD<<<NBK, 256, 0, stream>>>(ebuf, boff, colb, rowptr, N, NBK, E);

    int spmmblocks = (N + 3) / 4;  // 4 waves x 1 node per block
    // u = A*s0: gather fp8 s8, write u8 (fp8) + u16 (bf16)
    k_spmm<<<spmmblocks, 256, 0, stream>>>((const unsigned short*)s8, rowptr, colb,
                                           (const unsigned*)nullptr,
                                           (unsigned short*)u8, u16, 1, N);
    // v = A*u: gather fp8 u8 (self from bf16 u16), write v16 (bf16)
    k_spmm<<<spmmblocks, 256, 0, stream>>>((const unsigned short*)u8, rowptr, colb,
                                           u16, (unsigned short*)nullptr, v16, 0, N);

    int nrowtiles = (N + 15) / 16;
    int epiblocks = (nrowtiles + 3) / 4;
    k_epi<<<epiblocks, 256, 0, stream>>>((const unsigned short*)u16, (const unsigned short*)v16,
                                         wpack, features, invlp1, (float*)d_out, N);
}